// Round 6
// baseline (2817.372 us; speedup 1.0000x reference)
//
#include <hip/hip_runtime.h>

// VQ-VAE EMA vector quantizer, fp32.
// N=65536 rows (32*2048), D=256, K=1024 codes.
// Outputs (flat concat): z_q_st [N*D], vq_loss [1], codes [N] (as float),
//                        new_embedding [K*D], new_cluster_size [K], new_embed_avg [K*D]
//
// R3: z_sq in the distance fold (fp32 tie-rounding parity with ref).
// R4/R5: killed scratch spills (18.5 GB -> 0); 9.7 ms -> 1.23 ms.
// R6: two fixes from R5 counters (VALUBusy 46%, VGPR 252, ~1 block/CU):
//     (a) nested fmaf: 2 VALU ops / 2 MACs (was mul+fma+add = 3) -> 218 us floor
//     (b) occupancy: launch_bounds(256,3) + LDS 59.4->39.4 KB (LS=34, alias
//         post-GEMM reduction arrays onto tile buffers) -> 3+ blocks/CU.

#define DDIM 256
#define DQ   64      // DDIM/4
#define KC   1024
#define NROW 65536
#define BM   128     // rows per block
#define BN   128     // codes per k-tile
#define BD   32      // d-chunk
#define LS   34      // LDS row stride in floats: 34%32==2 (2-way aliasing = free), 136B %8==0 (b64 ok)
#define DECAYF 0.99f
#define OMDF   0.01f
#define BETAF  0.25f
#define EPSF   1e-5f

__global__ __launch_bounds__(256, 3) void vq_main(
    const float* __restrict__ z,         // [N, D]
    const float* __restrict__ emb,       // [K, D]
    float* __restrict__ out_zq,          // [N, D]
    float* __restrict__ out_codes,       // [N] (float-encoded ints)
    float* __restrict__ loss_acc)        // ws [1], pre-zeroed
{
    __shared__ float zs[BM * LS];        // 17408 B
    __shared__ float es[BN * LS];        // 17408 B
    __shared__ float esq_s[KC];          // 4096 B
    __shared__ float zsq_s[BM];          // 512 B   -> total 39424 B (4 blocks/CU fit)
    // post-GEMM aliases (guarded by __syncthreads before first use):
    float* red_v   = zs;                 // BM*16 = 2048 floats
    int*   red_i   = (int*)(zs + 2048);  // 2048 ints (zs has 4352 floats)
    int*   codes_s = (int*)es;           // 128 ints
    float* lred    = es + 128;           // 256 floats

    const int tid  = threadIdx.x;
    const int row0 = blockIdx.x * BM;
    const int trow = tid >> 4;           // 0..15
    const int tcol = tid & 15;           // 0..15

    // ---- prologue: ||e||^2 for all K codes, ||z||^2 for block rows ----
    for (int k = tid; k < KC; k += 256) {
        const float4* ep = (const float4*)(emb + (size_t)k * DDIM);
        float s = 0.f;
        for (int q = 0; q < DQ; ++q) {
            float4 v = ep[q];
            s += v.x * v.x + v.y * v.y + v.z * v.z + v.w * v.w;
        }
        esq_s[k] = s;
    }
    if (tid < BM) {
        const float4* zp = (const float4*)(z + (size_t)(row0 + tid) * DDIM);
        float s = 0.f;
        for (int q = 0; q < DQ; ++q) {
            float4 v = zp[q];
            s += v.x * v.x + v.y * v.y + v.z * v.z + v.w * v.w;
        }
        zsq_s[tid] = s;
    }

    float runv[8];
    int   runi[8];
#pragma unroll
    for (int i = 0; i < 8; ++i) { runv[i] = 3.4e38f; runi[i] = 0; }

    for (int kt = 0; kt < KC / BN; ++kt) {
        float acc[8][8];
#pragma unroll
        for (int i = 0; i < 8; ++i)
#pragma unroll
            for (int j = 0; j < 8; ++j) acc[i][j] = 0.f;

        for (int dc = 0; dc < DDIM / BD; ++dc) {
            __syncthreads();
#pragma unroll
            for (int it = 0; it < 4; ++it) {
                int chunk = tid + it * 256;     // 0..1023
                int r = chunk >> 3;
                int q = chunk & 7;
                float4 zv = *(const float4*)(z + (size_t)(row0 + r) * DDIM + dc * BD + q * 4);
                *(float2*)(zs + r * LS + q * 4)     = make_float2(zv.x, zv.y);
                *(float2*)(zs + r * LS + q * 4 + 2) = make_float2(zv.z, zv.w);
                float4 ev = *(const float4*)(emb + (size_t)(kt * BN + r) * DDIM + dc * BD + q * 4);
                *(float2*)(es + r * LS + q * 4)     = make_float2(ev.x, ev.y);
                *(float2*)(es + r * LS + q * 4 + 2) = make_float2(ev.z, ev.w);
            }
            __syncthreads();
#pragma unroll
            for (int s = 0; s < BD / 2; ++s) {
                float2 a2[8], b2[8];
#pragma unroll
                for (int i = 0; i < 8; ++i)
                    a2[i] = *(const float2*)(zs + (trow + 16 * i) * LS + s * 2);
#pragma unroll
                for (int j = 0; j < 8; ++j)
                    b2[j] = *(const float2*)(es + (tcol + 16 * j) * LS + s * 2);
#pragma unroll
                for (int i = 0; i < 8; ++i)
#pragma unroll
                    for (int j = 0; j < 8; ++j)
                        acc[i][j] = fmaf(a2[i].y, b2[j].y,
                                     fmaf(a2[i].x, b2[j].x, acc[i][j]));
            }
        }

        // fold this k-tile into the running argmin (cols scanned ascending, strict <).
        // Association order matches reference: (z_sq - 2*acc) + e_sq.
#pragma unroll
        for (int i = 0; i < 8; ++i) {
            float zq2 = zsq_s[trow + 16 * i];
#pragma unroll
            for (int j = 0; j < 8; ++j) {
                int col = kt * BN + tcol + 16 * j;
                float dist = zq2 - 2.f * acc[i][j] + esq_s[col];
                if (dist < runv[i]) { runv[i] = dist; runi[i] = col; }
            }
        }
    }

    // ---- cross-thread argmin combine (16 col-threads per row) ----
    __syncthreads();                     // GEMM reads of zs/es done before aliasing
#pragma unroll
    for (int i = 0; i < 8; ++i) {
        int lr = trow + 16 * i;
        red_v[lr * 16 + tcol] = runv[i];
        red_i[lr * 16 + tcol] = runi[i];
    }
    __syncthreads();
    if (tid < BM) {
        float bv = red_v[tid * 16];
        int   bi = red_i[tid * 16];
        for (int t = 1; t < 16; ++t) {
            float v  = red_v[tid * 16 + t];
            int   ix = red_i[tid * 16 + t];
            if (v < bv || (v == bv && ix < bi)) { bv = v; bi = ix; }
        }
        codes_s[tid] = bi;
        out_codes[row0 + tid] = (float)bi;
    }
    __syncthreads();

    // ---- epilogue: gather z_q, write z_q_st, commit-loss partial ----
    const int wave = tid >> 6;
    const int lane = tid & 63;
    float lp = 0.f;
    for (int r = wave; r < BM; r += 4) {
        int code = codes_s[r];
        float4 e4 = *(const float4*)(emb + (size_t)code * DDIM + lane * 4);
        float4 z4 = *(const float4*)(z + (size_t)(row0 + r) * DDIM + lane * 4);
        float dx = e4.x - z4.x, dy = e4.y - z4.y, dz = e4.z - z4.z, dw = e4.w - z4.w;
        float4 o;
        o.x = z4.x + dx; o.y = z4.y + dy; o.z = z4.z + dz; o.w = z4.w + dw;  // z_e + (z_q - z_e)
        *(float4*)(out_zq + (size_t)(row0 + r) * DDIM + lane * 4) = o;
        lp += dx * dx + dy * dy + dz * dz + dw * dw;
    }
    lred[tid] = lp;
    __syncthreads();
    for (int s = 128; s > 0; s >>= 1) {
        if (tid < s) lred[tid] += lred[tid + s];
        __syncthreads();
    }
    if (tid == 0) atomicAdd(loss_acc, lred[0]);
}

// One block per code k. Scan codes (L2-resident), gather matching z rows
// coalesced, direct-write embed_sum[k,:] and counts[k]. Zero global atomics.
__global__ __launch_bounds__(256) void vq_scatter(
    const float* __restrict__ z,
    const float* __restrict__ codes_f,
    float* __restrict__ embed_sum,
    float* __restrict__ counts)
{
    __shared__ int list[1024];
    __shared__ int nmatch;
    const int k   = blockIdx.x;
    const int tid = threadIdx.x;

    float acc = 0.f;
    int total = 0;
    if (tid == 0) nmatch = 0;
    __syncthreads();

    for (int base = 0; base < NROW; base += 1024) {
        float4 c4 = *(const float4*)(codes_f + base + tid * 4);
        int i0 = base + tid * 4;
        if ((int)c4.x == k) { int p = atomicAdd(&nmatch, 1); list[p] = i0; }
        if ((int)c4.y == k) { int p = atomicAdd(&nmatch, 1); list[p] = i0 + 1; }
        if ((int)c4.z == k) { int p = atomicAdd(&nmatch, 1); list[p] = i0 + 2; }
        if ((int)c4.w == k) { int p = atomicAdd(&nmatch, 1); list[p] = i0 + 3; }
        __syncthreads();
        int nm = nmatch;
        for (int i = 0; i < nm; ++i)
            acc += z[(size_t)list[i] * DDIM + tid];   // coalesced 1KB row read
        total += nm;
        __syncthreads();
        if (tid == 0) nmatch = 0;
        __syncthreads();
    }
    embed_sum[(size_t)k * DDIM + tid] = acc;
    if (tid == 0) counts[k] = (float)total;
}

__global__ void vq_finalize(const float* __restrict__ cluster_size,
                            const float* __restrict__ counts,
                            const float* __restrict__ loss_acc,
                            float* __restrict__ out_ncs,
                            float* __restrict__ out_loss,
                            float* __restrict__ cs_sm,
                            float inv_ND)
{
    __shared__ float sred[KC];
    const int tid = threadIdx.x;
    float ncs = cluster_size[tid] * DECAYF + counts[tid] * OMDF;
    out_ncs[tid] = ncs;
    sred[tid] = ncs;
    __syncthreads();
    for (int s = KC / 2; s > 0; s >>= 1) {
        if (tid < s) sred[tid] += sred[tid + s];
        __syncthreads();
    }
    float n = sred[0];
    cs_sm[tid] = (ncs + EPSF) / (n + (float)KC * EPSF) * n;
    if (tid == 0) out_loss[0] = BETAF * loss_acc[0] * inv_ND;
}

__global__ void vq_embed(const float* __restrict__ embed_avg,
                         const float* __restrict__ embed_sum,
                         const float* __restrict__ cs_sm,
                         float* __restrict__ out_nea,
                         float* __restrict__ out_nemb)
{
    int idx = blockIdx.x * blockDim.x + threadIdx.x;   // float4 index
    int k = idx >> 6;                                   // 64 float4 per code row
    float4 ea = ((const float4*)embed_avg)[idx];
    float4 s4 = ((const float4*)embed_sum)[idx];
    float4 nea;
    nea.x = ea.x * DECAYF + s4.x * OMDF;
    nea.y = ea.y * DECAYF + s4.y * OMDF;
    nea.z = ea.z * DECAYF + s4.z * OMDF;
    nea.w = ea.w * DECAYF + s4.w * OMDF;
    ((float4*)out_nea)[idx] = nea;
    float cs = cs_sm[k];
    float4 ne;
    ne.x = nea.x / cs; ne.y = nea.y / cs; ne.z = nea.z / cs; ne.w = nea.w / cs;
    ((float4*)out_nemb)[idx] = ne;
}

extern "C" void kernel_launch(void* const* d_in, const int* in_sizes, int n_in,
                              void* d_out, int out_size, void* d_ws, size_t ws_size,
                              hipStream_t stream) {
    const float* z            = (const float*)d_in[0];   // [N, 256]
    const float* emb          = (const float*)d_in[1];   // [1024, 256]
    const float* cluster_size = (const float*)d_in[2];   // [1024]
    const float* embed_avg    = (const float*)d_in[3];   // [1024, 256]

    const int ND = in_sizes[0];       // N*D = 16777216
    const int KD = in_sizes[1];       // K*D = 262144
    const int K  = in_sizes[2];       // 1024
    const int N  = ND / DDIM;         // 65536

    float* out       = (float*)d_out;
    float* out_zq    = out;                              // [N*D]
    float* out_loss  = out + (size_t)ND;                 // [1]
    float* out_codes = out + (size_t)ND + 1;             // [N]
    float* out_nemb  = out + (size_t)ND + 1 + N;         // [K*D]
    float* out_ncs   = out_nemb + (size_t)KD;            // [K]
    float* out_nea   = out_ncs + (size_t)K;              // [K*D]

    float* ws        = (float*)d_ws;
    float* loss_acc  = ws;                 // [1]
    float* counts    = ws + 1;             // [K]
    float* cs_sm     = counts + K;         // [K]
    float* embed_sum = cs_sm + K;          // [K*D]

    hipMemsetAsync(loss_acc, 0, sizeof(float), stream);
    vq_main<<<N / BM, 256, 0, stream>>>(z, emb, out_zq, out_codes, loss_acc);
    vq_scatter<<<K, 256, 0, stream>>>(z, out_codes, embed_sum, counts);
    vq_finalize<<<1, K, 0, stream>>>(cluster_size, counts, loss_acc,
                                     out_ncs, out_loss, cs_sm, 1.0f / (float)ND);
    vq_embed<<<KD / 1024, 256, 0, stream>>>(embed_avg, embed_sum, cs_sm,
                                            out_nea, out_nemb);
}

// Round 7
// 910.854 us; speedup vs baseline: 3.0931x; 3.0931x over previous
//
#include <hip/hip_runtime.h>

// VQ-VAE EMA vector quantizer, fp32.
// N=65536 rows (32*2048), D=256, K=1024 codes.
// Outputs (flat concat): z_q_st [N*D], vq_loss [1], codes [N] (as float),
//                        new_embedding [K*D], new_cluster_size [K], new_embed_avg [K*D]
//
// R3: z_sq in distance fold (fp32 tie-rounding parity with numpy ref).
// R4/R5: killed scratch spills (18.5 GB -> 0); 9.7 ms -> 1.23 ms.
// R6 FAILED: __launch_bounds__(256,3) made allocator target ~84 VGPR -> acc
//     spilled (5 GB scratch). NEVER force occupancy via launch_bounds here.
// R7: (a) register prefetch pipeline: global load of tile (kt,dc+1) issued
//     after the post-stage barrier, overlapping the ~380-cyc compute -> the
//     exposed 200-900 cyc VMEM latency per dc-iter (R5's 54% stall) hides.
//     (b) ||e||^2 hoisted to one-shot vq_esq kernel (was 1 MB reads + 65k
//     FMAs per block). (c) fmaf nesting kept, unroll 1 on kt/dc to hold
//     live regs ~165.

#define DDIM 256
#define DQ   64      // DDIM/4
#define KC   1024
#define NROW 65536
#define BM   128     // rows per block
#define BN   128     // codes per k-tile
#define BD   32      // d-chunk
#define LS   34      // LDS row stride in floats: 34%32==2 (2-way aliasing = free), 136B, 8B-aligned accesses
#define DECAYF 0.99f
#define OMDF   0.01f
#define BETAF  0.25f
#define EPSF   1e-5f

// one-shot ||e||^2 for all codes
__global__ __launch_bounds__(256) void vq_esq(const float* __restrict__ emb,
                                              float* __restrict__ esq_g)
{
    int k = blockIdx.x * 256 + threadIdx.x;   // grid = KC/256 blocks
    const float4* ep = (const float4*)(emb + (size_t)k * DDIM);
    float s = 0.f;
    for (int q = 0; q < DQ; ++q) {
        float4 v = ep[q];
        s += v.x * v.x + v.y * v.y + v.z * v.z + v.w * v.w;
    }
    esq_g[k] = s;
}

__global__ __launch_bounds__(256) void vq_main(
    const float* __restrict__ z,         // [N, D]
    const float* __restrict__ emb,       // [K, D]
    const float* __restrict__ esq_g,     // [K] precomputed ||e||^2
    float* __restrict__ out_zq,          // [N, D]
    float* __restrict__ out_codes,       // [N] (float-encoded ints)
    float* __restrict__ loss_acc)        // ws [1], pre-zeroed
{
    __shared__ float zs[BM * LS];        // 17408 B
    __shared__ float es[BN * LS];        // 17408 B
    __shared__ float esq_s[KC];          // 4096 B
    __shared__ float zsq_s[BM];          // 512 B   -> 39424 B total
    // post-GEMM aliases (guarded by __syncthreads before first use):
    float* red_v   = zs;                 // BM*16 floats
    int*   red_i   = (int*)(zs + 2048);  // BM*16 ints
    int*   codes_s = (int*)es;           // BM ints
    float* lred    = es + 128;           // 256 floats

    const int tid  = threadIdx.x;
    const int row0 = blockIdx.x * BM;
    const int trow = tid >> 4;           // 0..15
    const int tcol = tid & 15;           // 0..15

    // ---- prologue: load ||e||^2, compute ||z||^2 for block rows ----
    {
        const float4* eg = (const float4*)esq_g;
        float4 v = eg[tid];              // 256 threads x float4 = 1024
        *(float4*)(esq_s + tid * 4) = v;
    }
    if (tid < BM) {
        const float4* zp = (const float4*)(z + (size_t)(row0 + tid) * DDIM);
        float s = 0.f;
        for (int q = 0; q < DQ; ++q) {
            float4 v = zp[q];
            s += v.x * v.x + v.y * v.y + v.z * v.z + v.w * v.w;
        }
        zsq_s[tid] = s;
    }

    // staging descriptors: chunk = tid + 256*it -> r = r0 + 32*it, q = tid&7
    const int r0 = tid >> 3;
    const int q0 = tid & 7;
    const float* zp0 = z + (size_t)(row0 + r0) * DDIM + q0 * 4;  // + it*32*DDIM + dc*BD
    const float* ep0 = emb + (size_t)r0 * DDIM + q0 * 4;         // + it*32*DDIM + kt*BN*DDIM + dc*BD
    const int ls0 = r0 * LS + q0 * 4;                            // + it*32*LS

    float4 pz[4], pe[4];
#pragma unroll
    for (int it = 0; it < 4; ++it) {                             // prefetch kt=0, dc=0
        pz[it] = *(const float4*)(zp0 + it * 32 * DDIM);
        pe[it] = *(const float4*)(ep0 + it * 32 * DDIM);
    }

    float runv[8];
    int   runi[8];
#pragma unroll
    for (int i = 0; i < 8; ++i) { runv[i] = 3.4e38f; runi[i] = 0; }

#pragma unroll 1
    for (int kt = 0; kt < KC / BN; ++kt) {
        float acc[8][8];
#pragma unroll
        for (int i = 0; i < 8; ++i)
#pragma unroll
            for (int j = 0; j < 8; ++j) acc[i][j] = 0.f;

#pragma unroll 1
        for (int dc = 0; dc < DDIM / BD; ++dc) {
            __syncthreads();
#pragma unroll
            for (int it = 0; it < 4; ++it) {
                int o = ls0 + it * 32 * LS;
                *(float2*)(zs + o)     = make_float2(pz[it].x, pz[it].y);
                *(float2*)(zs + o + 2) = make_float2(pz[it].z, pz[it].w);
                *(float2*)(es + o)     = make_float2(pe[it].x, pe[it].y);
                *(float2*)(es + o + 2) = make_float2(pe[it].z, pe[it].w);
            }
            __syncthreads();

            // prefetch next (kt,dc) while computing on the staged tile
            {
                int ndc = dc + 1, nkt = kt;
                if (ndc == DDIM / BD) { ndc = 0; ++nkt; }
                if (nkt < KC / BN) {
                    size_t zo = (size_t)ndc * BD;
                    size_t eo = (size_t)nkt * BN * DDIM + (size_t)ndc * BD;
#pragma unroll
                    for (int it = 0; it < 4; ++it) {
                        pz[it] = *(const float4*)(zp0 + it * 32 * DDIM + zo);
                        pe[it] = *(const float4*)(ep0 + it * 32 * DDIM + eo);
                    }
                }
            }

#pragma unroll
            for (int s = 0; s < BD / 2; ++s) {
                float2 a2[8], b2[8];
#pragma unroll
                for (int i = 0; i < 8; ++i)
                    a2[i] = *(const float2*)(zs + (trow + 16 * i) * LS + s * 2);
#pragma unroll
                for (int j = 0; j < 8; ++j)
                    b2[j] = *(const float2*)(es + (tcol + 16 * j) * LS + s * 2);
#pragma unroll
                for (int i = 0; i < 8; ++i)
#pragma unroll
                    for (int j = 0; j < 8; ++j)
                        acc[i][j] = fmaf(a2[i].y, b2[j].y,
                                     fmaf(a2[i].x, b2[j].x, acc[i][j]));
            }
        }

        // fold this k-tile into the running argmin (cols scanned ascending, strict <).
        // Association order matches reference: (z_sq - 2*acc) + e_sq.
#pragma unroll
        for (int i = 0; i < 8; ++i) {
            float zq2 = zsq_s[trow + 16 * i];
#pragma unroll
            for (int j = 0; j < 8; ++j) {
                int col = kt * BN + tcol + 16 * j;
                float dist = zq2 - 2.f * acc[i][j] + esq_s[col];
                if (dist < runv[i]) { runv[i] = dist; runi[i] = col; }
            }
        }
    }

    // ---- cross-thread argmin combine (16 col-threads per row) ----
    __syncthreads();                     // GEMM reads of zs/es done before aliasing
#pragma unroll
    for (int i = 0; i < 8; ++i) {
        int lr = trow + 16 * i;
        red_v[lr * 16 + tcol] = runv[i];
        red_i[lr * 16 + tcol] = runi[i];
    }
    __syncthreads();
    if (tid < BM) {
        float bv = red_v[tid * 16];
        int   bi = red_i[tid * 16];
        for (int t = 1; t < 16; ++t) {
            float v  = red_v[tid * 16 + t];
            int   ix = red_i[tid * 16 + t];
            if (v < bv || (v == bv && ix < bi)) { bv = v; bi = ix; }
        }
        codes_s[tid] = bi;
        out_codes[row0 + tid] = (float)bi;
    }
    __syncthreads();

    // ---- epilogue: gather z_q, write z_q_st, commit-loss partial ----
    const int wave = tid >> 6;
    const int lane = tid & 63;
    float lp = 0.f;
    for (int r = wave; r < BM; r += 4) {
        int code = codes_s[r];
        float4 e4 = *(const float4*)(emb + (size_t)code * DDIM + lane * 4);
        float4 z4 = *(const float4*)(z + (size_t)(row0 + r) * DDIM + lane * 4);
        float dx = e4.x - z4.x, dy = e4.y - z4.y, dz = e4.z - z4.z, dw = e4.w - z4.w;
        float4 o;
        o.x = z4.x + dx; o.y = z4.y + dy; o.z = z4.z + dz; o.w = z4.w + dw;  // z_e + (z_q - z_e)
        *(float4*)(out_zq + (size_t)(row0 + r) * DDIM + lane * 4) = o;
        lp += dx * dx + dy * dy + dz * dz + dw * dw;
    }
    lred[tid] = lp;
    __syncthreads();
    for (int s = 128; s > 0; s >>= 1) {
        if (tid < s) lred[tid] += lred[tid + s];
        __syncthreads();
    }
    if (tid == 0) atomicAdd(loss_acc, lred[0]);
}

// One block per code k. Scan codes (L2-resident), gather matching z rows
// coalesced, direct-write embed_sum[k,:] and counts[k]. Zero global atomics.
__global__ __launch_bounds__(256) void vq_scatter(
    const float* __restrict__ z,
    const float* __restrict__ codes_f,
    float* __restrict__ embed_sum,
    float* __restrict__ counts)
{
    __shared__ int list[1024];
    __shared__ int nmatch;
    const int k   = blockIdx.x;
    const int tid = threadIdx.x;

    float acc = 0.f;
    int total = 0;
    if (tid == 0) nmatch = 0;
    __syncthreads();

    for (int base = 0; base < NROW; base += 1024) {
        float4 c4 = *(const float4*)(codes_f + base + tid * 4);
        int i0 = base + tid * 4;
        if ((int)c4.x == k) { int p = atomicAdd(&nmatch, 1); list[p] = i0; }
        if ((int)c4.y == k) { int p = atomicAdd(&nmatch, 1); list[p] = i0 + 1; }
        if ((int)c4.z == k) { int p = atomicAdd(&nmatch, 1); list[p] = i0 + 2; }
        if ((int)c4.w == k) { int p = atomicAdd(&nmatch, 1); list[p] = i0 + 3; }
        __syncthreads();
        int nm = nmatch;
        for (int i = 0; i < nm; ++i)
            acc += z[(size_t)list[i] * DDIM + tid];   // coalesced 1KB row read
        total += nm;
        __syncthreads();
        if (tid == 0) nmatch = 0;
        __syncthreads();
    }
    embed_sum[(size_t)k * DDIM + tid] = acc;
    if (tid == 0) counts[k] = (float)total;
}

__global__ void vq_finalize(const float* __restrict__ cluster_size,
                            const float* __restrict__ counts,
                            const float* __restrict__ loss_acc,
                            float* __restrict__ out_ncs,
                            float* __restrict__ out_loss,
                            float* __restrict__ cs_sm,
                            float inv_ND)
{
    __shared__ float sred[KC];
    const int tid = threadIdx.x;
    float ncs = cluster_size[tid] * DECAYF + counts[tid] * OMDF;
    out_ncs[tid] = ncs;
    sred[tid] = ncs;
    __syncthreads();
    for (int s = KC / 2; s > 0; s >>= 1) {
        if (tid < s) sred[tid] += sred[tid + s];
        __syncthreads();
    }
    float n = sred[0];
    cs_sm[tid] = (ncs + EPSF) / (n + (float)KC * EPSF) * n;
    if (tid == 0) out_loss[0] = BETAF * loss_acc[0] * inv_ND;
}

__global__ void vq_embed(const float* __restrict__ embed_avg,
                         const float* __restrict__ embed_sum,
                         const float* __restrict__ cs_sm,
                         float* __restrict__ out_nea,
                         float* __restrict__ out_nemb)
{
    int idx = blockIdx.x * blockDim.x + threadIdx.x;   // float4 index
    int k = idx >> 6;                                   // 64 float4 per code row
    float4 ea = ((const float4*)embed_avg)[idx];
    float4 s4 = ((const float4*)embed_sum)[idx];
    float4 nea;
    nea.x = ea.x * DECAYF + s4.x * OMDF;
    nea.y = ea.y * DECAYF + s4.y * OMDF;
    nea.z = ea.z * DECAYF + s4.z * OMDF;
    nea.w = ea.w * DECAYF + s4.w * OMDF;
    ((float4*)out_nea)[idx] = nea;
    float cs = cs_sm[k];
    float4 ne;
    ne.x = nea.x / cs; ne.y = nea.y / cs; ne.z = nea.z / cs; ne.w = nea.w / cs;
    ((float4*)out_nemb)[idx] = ne;
}

extern "C" void kernel_launch(void* const* d_in, const int* in_sizes, int n_in,
                              void* d_out, int out_size, void* d_ws, size_t ws_size,
                              hipStream_t stream) {
    const float* z            = (const float*)d_in[0];   // [N, 256]
    const float* emb          = (const float*)d_in[1];   // [1024, 256]
    const float* cluster_size = (const float*)d_in[2];   // [1024]
    const float* embed_avg    = (const float*)d_in[3];   // [1024, 256]

    const int ND = in_sizes[0];       // N*D = 16777216
    const int KD = in_sizes[1];       // K*D = 262144
    const int K  = in_sizes[2];       // 1024
    const int N  = ND / DDIM;         // 65536

    float* out       = (float*)d_out;
    float* out_zq    = out;                              // [N*D]
    float* out_loss  = out + (size_t)ND;                 // [1]
    float* out_codes = out + (size_t)ND + 1;             // [N]
    float* out_nemb  = out + (size_t)ND + 1 + N;         // [K*D]
    float* out_ncs   = out_nemb + (size_t)KD;            // [K]
    float* out_nea   = out_ncs + (size_t)K;              // [K*D]

    float* ws        = (float*)d_ws;
    float* loss_acc  = ws;                 // [1]
    float* counts    = ws + 1;             // [K]
    float* cs_sm     = counts + K;         // [K]
    float* esq_g     = cs_sm + K;          // [K]
    float* embed_sum = esq_g + K;          // [K*D]

    hipMemsetAsync(loss_acc, 0, sizeof(float), stream);
    vq_esq<<<K / 256, 256, 0, stream>>>(emb, esq_g);
    vq_main<<<N / BM, 256, 0, stream>>>(z, emb, esq_g, out_zq, out_codes, loss_acc);
    vq_scatter<<<K, 256, 0, stream>>>(z, out_codes, embed_sum, counts);
    vq_finalize<<<1, K, 0, stream>>>(cluster_size, counts, loss_acc,
                                     out_ncs, out_loss, cs_sm, 1.0f / (float)ND);
    vq_embed<<<KD / 1024, 256, 0, stream>>>(embed_avg, embed_sum, cs_sm,
                                            out_nea, out_nemb);
}